// Round 3
// baseline (482.815 us; speedup 1.0000x reference)
//
#include <hip/hip_runtime.h>

typedef __bf16 bf16x8 __attribute__((ext_vector_type(8)));
typedef __bf16 bf16x4 __attribute__((ext_vector_type(4)));
typedef float floatx4 __attribute__((ext_vector_type(4)));

#define GK 2048
#define S_LEN 2048
#define NH 16
#define DH 128

__device__ __forceinline__ void gl2lds16(const __bf16* g, __bf16* l) {
    __builtin_amdgcn_global_load_lds(
        (const __attribute__((address_space(1))) void*)g,
        (__attribute__((address_space(3))) void*)l, 16, 0, 0);
}
__device__ __forceinline__ void gl2lds16c(const __bf16* g, char* l) {
    __builtin_amdgcn_global_load_lds(
        (const __attribute__((address_space(1))) void*)g,
        (__attribute__((address_space(3))) void*)l, 16, 0, 0);
}

// ---------------------------------------------------------------------------
// fp32 -> bf16 bulk convert (one float4 -> bf16x4 per thread)
// ---------------------------------------------------------------------------
__global__ __launch_bounds__(256) void cvt_bf16(const float* __restrict__ in,
                                                __bf16* __restrict__ out, int n4) {
    int i = blockIdx.x * 256 + threadIdx.x;
    if (i < n4) {
        const float4 v = ((const float4*)in)[i];
        bf16x4 h;
        h[0] = (__bf16)v.x; h[1] = (__bf16)v.y; h[2] = (__bf16)v.z; h[3] = (__bf16)v.w;
        ((bf16x4*)out)[i] = h;
    }
}

// concat-convert wq|wk|wv (each 2048x2048 fp32) -> one bf16 [6144][2048]
__global__ __launch_bounds__(256) void cvt3_bf16(const float* __restrict__ a,
                                                 const float* __restrict__ b,
                                                 const float* __restrict__ c,
                                                 __bf16* __restrict__ out) {
    const int per = 2048 * 2048 / 4;
    int i = blockIdx.x * 256 + threadIdx.x;      // 0 .. 3*per-1
    const float* src = a; int j = i;
    if (i >= 2 * per)      { src = c; j = i - 2 * per; }
    else if (i >= per)     { src = b; j = i - per; }
    const float4 v = ((const float4*)src)[j];
    bf16x4 h;
    h[0] = (__bf16)v.x; h[1] = (__bf16)v.y; h[2] = (__bf16)v.z; h[3] = (__bf16)v.w;
    ((bf16x4*)out)[i] = h;
}

// XCD-aware bijective remap of a linear block id (nwg must be %8==0).
__device__ __forceinline__ int xcd_remap(int L, int nwg) {
    return (L & 7) * (nwg >> 3) + (L >> 3);
}

// ---------------------------------------------------------------------------
// Deep-pipelined GEMM body: C[m][n] = sum_k A[m][k] * W[n][k].
// Tile 128(M) x 256(N), BK=64, 8 waves (2m x 4n), per-wave 64x64 out.
// - double-buffered LDS (2 x 48KB, dynamic), global_load_lds width-16
// - cross-iteration prefetch with counted s_waitcnt vmcnt(6) (T4): tile t+1's
//   loads are issued at end of iter t-1 and waited at end of iter t.
//   WAR-safe: stage into buf b only after the barrier ending b's compute.
// - T2 XOR swizzle, rule-21 pattern: linear LDS dest + inverse-swizzled
//   per-lane GLOBAL source + swizzled ds_read (byte ^= (row&7)<<4).
// LDS layout per buffer: [A 128x64 @0 (16KB)][B 256x64 @16KB (32KB)],
// row stride 128B; element (r,c) at byte r*128 + (2c ^ ((r&7)<<4)).
// ---------------------------------------------------------------------------
__device__ __forceinline__ void gemm_body2(const __bf16* __restrict__ A,
                                           const __bf16* __restrict__ W,
                                           int m0, int n0, char* lds,
                                           floatx4 (*acc)[4]) {
    const int t = threadIdx.x, lane = t & 63, wave = t >> 6;
    const int fr = lane & 15, fq = lane >> 4;
    const int wm = wave >> 2, wn = wave & 3;
    const int NKT = GK / 64;

    // staging: wave w, round c covers rows c*64 + w*8 + (lane>>3); the lane's
    // global column is pre-swizzled so the linear LDS write lands swizzled.
    const int swcol = ((lane & 7) * 8) ^ ((lane >> 3) * 8);   // elements
    const __bf16* gA = A + (size_t)(m0 + wave * 8 + (lane >> 3)) * GK + swcol;
    const __bf16* gW = W + (size_t)(n0 + wave * 8 + (lane >> 3)) * GK + swcol;
    char* const sAw = lds + wave * 1024;            // + b*49152 + c*8192
    char* const sBw = lds + 16384 + wave * 1024;

    auto STAGE = [&](int b, int kt) {
        const __bf16* a = gA + (size_t)kt * 64;
        const __bf16* w = gW + (size_t)kt * 64;
        char* la = sAw + b * 49152;
        char* lb = sBw + b * 49152;
        gl2lds16c(a,                      la);
        gl2lds16c(a + (size_t)64 * GK,    la + 8192);
        gl2lds16c(w,                      lb);
        gl2lds16c(w + (size_t)64 * GK,    lb + 8192);
        gl2lds16c(w + (size_t)128 * GK,   lb + 16384);
        gl2lds16c(w + (size_t)192 * GK,   lb + 24576);
    };

    STAGE(0, 0);
    STAGE(1, 1);
    asm volatile("s_waitcnt vmcnt(6)" ::: "memory");   // tile 0 landed
    __syncthreads();

    const int sw = (fr & 7) << 4;
    const int c0b = (fq * 16) ^ sw;          // ks=0 byte offset in row
    const int c1b = (64 + fq * 16) ^ sw;     // ks=1

    for (int t0 = 0; t0 < NKT; t0++) {
        const char* bufb = lds + (t0 & 1) * 49152;

        bf16x8 bfr[4][2];
#pragma unroll
        for (int j = 0; j < 4; j++) {
            const char* rb = bufb + 16384 + (wn * 64 + j * 16 + fr) * 128;
            bfr[j][0] = *(const bf16x8*)(rb + c0b);
            bfr[j][1] = *(const bf16x8*)(rb + c1b);
        }
#pragma unroll
        for (int i = 0; i < 4; i++) {
            const char* ra = bufb + (wm * 64 + i * 16 + fr) * 128;
            const bf16x8 a0 = *(const bf16x8*)(ra + c0b);
            const bf16x8 a1 = *(const bf16x8*)(ra + c1b);
            __builtin_amdgcn_s_setprio(1);
#pragma unroll
            for (int j = 0; j < 4; j++) {
                acc[i][j] = __builtin_amdgcn_mfma_f32_16x16x32_bf16(a0, bfr[j][0], acc[i][j], 0, 0, 0);
                acc[i][j] = __builtin_amdgcn_mfma_f32_16x16x32_bf16(a1, bfr[j][1], acc[i][j], 0, 0, 0);
            }
            __builtin_amdgcn_s_setprio(0);
        }
        __syncthreads();                     // all waves done reading buf b
        if (t0 + 2 < NKT) {
            STAGE(t0 & 1, t0 + 2);           // overwrite b, safe after barrier
            asm volatile("s_waitcnt vmcnt(6)" ::: "memory");  // tile t0+1 landed
        } else {
            asm volatile("s_waitcnt vmcnt(0)" ::: "memory");
        }
        __syncthreads();                     // tile t0+1 visible to all waves
    }
}

// Fused QKV projection: A (4096x2048 bf16) x Wqkv (6144x2048 bf16).
// n<2048 -> qb, n<4096 -> kb (row-major [b*S][2048]); n>=4096 -> vbT
// ([b][h*128+d][s], transposed for flash staging).
__global__ __launch_bounds__(512, 2) void gemm_qkv(const __bf16* __restrict__ A,
                                                   const __bf16* __restrict__ W,
                                                   __bf16* __restrict__ qb,
                                                   __bf16* __restrict__ kb,
                                                   __bf16* __restrict__ vbT) {
    extern __shared__ __align__(16) char lds[];
    const int gx = gridDim.x;                         // 24
    const int L = blockIdx.x + gx * blockIdx.y;
    const int tid2 = xcd_remap(L, gx * (int)gridDim.y);
    const int m0 = (tid2 / gx) * 128, n0 = (tid2 % gx) * 256;
    floatx4 acc[4][4] = {};
    gemm_body2(A, W, m0, n0, lds, acc);

    const int lane = threadIdx.x & 63, wave = threadIdx.x >> 6;
    const int fr = lane & 15, fq = lane >> 4;
    const int wm = wave >> 2, wn = wave & 3;
    const int which = n0 >> 11;          // 0=q 1=k 2=v (block-uniform, 256|2048)
    const int nc0 = n0 & 2047;

    for (int i = 0; i < 4; i++)
        for (int j = 0; j < 4; j++) {
            const int row = m0 + wm * 64 + i * 16 + fq * 4;
            const int col = nc0 + wn * 64 + j * 16 + fr;
            if (which == 2) {
                // vbT[b][col][s]; b = row>>11, s = row&2047 (row%4==0 -> 8B aligned)
                __bf16* Cp = vbT + (((size_t)(row & ~2047)) << 11) +
                             (size_t)col * 2048 + (row & 2047);
                bf16x4 hv;
                for (int r = 0; r < 4; r++) hv[r] = (__bf16)acc[i][j][r];
                *(bf16x4*)Cp = hv;
            } else {
                __bf16* dst = which ? kb : qb;
                for (int r = 0; r < 4; r++)
                    dst[(size_t)(row + r) * 2048 + col] = (__bf16)acc[i][j][r];
            }
        }
}

// Out-projection: A (4096x2048 bf16) x Wo (2048x2048 bf16) -> fp32 out
__global__ __launch_bounds__(512, 2) void gemm_out(const __bf16* __restrict__ A,
                                                   const __bf16* __restrict__ W,
                                                   float* __restrict__ C) {
    extern __shared__ __align__(16) char lds[];
    const int gx = gridDim.x;                         // 8
    const int L = blockIdx.x + gx * blockIdx.y;
    const int tid2 = xcd_remap(L, gx * (int)gridDim.y);
    const int m0 = (tid2 / gx) * 128, n0 = (tid2 % gx) * 256;
    floatx4 acc[4][4] = {};
    gemm_body2(A, W, m0, n0, lds, acc);

    const int lane = threadIdx.x & 63, wave = threadIdx.x >> 6;
    const int fr = lane & 15, fq = lane >> 4;
    const int wm = wave >> 2, wn = wave & 3;
    for (int i = 0; i < 4; i++)
        for (int j = 0; j < 4; j++) {
            const int row = m0 + wm * 64 + i * 16 + fq * 4;
            const int col = n0 + wn * 64 + j * 16 + fr;
            for (int r = 0; r < 4; r++)
                C[(size_t)(row + r) * 2048 + col] = acc[i][j][r];
        }
}

// ---------------------------------------------------------------------------
// Fused RMSNorm (per head, DH=128, fp32 math) + RoPE, in-place on bf16 q/k.
// ---------------------------------------------------------------------------
__global__ __launch_bounds__(256) void rmsrope(__bf16* __restrict__ qb,
                                               __bf16* __restrict__ kb,
                                               const float* __restrict__ rope,
                                               const float* __restrict__ qw,
                                               const float* __restrict__ kw) {
    const int lane = threadIdx.x & 63;
    const int row = blockIdx.x * 4 + (threadIdx.x >> 6);   // (b*S + s)*H + h
    __bf16* p = (blockIdx.y ? kb : qb) + (size_t)row * DH;
    const float* w = blockIdx.y ? kw : qw;
    const int s = (row >> 4) & (S_LEN - 1);

    float t0 = (float)p[lane];
    float t1 = (float)p[lane + 64];
    float ss = t0 * t0 + t1 * t1;
    for (int o = 32; o; o >>= 1) ss += __shfl_xor(ss, o, 64);
    const float inv = rsqrtf(ss * (1.0f / 128.0f) + 1e-6f);
    t0 *= inv * w[lane];
    t1 *= inv * w[lane + 64];

    const float4 f = *(const float4*)(rope + (size_t)s * 256 + lane * 4);
    p[lane]      = (__bf16)(f.x * t0 + f.y * t1);
    p[lane + 64] = (__bf16)(f.z * t0 + f.w * t1);
}

// ---------------------------------------------------------------------------
// Flash attention (round-2 version, unchanged): fixed-max softmax
// (p = exp2(s*sc*log2e - M2)), l via MFMA ones-column.
// grid = (S/128, B*H), 4 waves x 32 q-rows, KV tile 32.
// XCD remap: all 16 q-blocks of 4 heads share one XCD -> K/V (4 MB) lives in
// that XCD's L2 (round-1 evidence: FETCH 139 MB -> 33 MB).
// ---------------------------------------------------------------------------
__global__ __launch_bounds__(256) void flash(const __bf16* __restrict__ Q,
                                             const __bf16* __restrict__ K,
                                             const __bf16* __restrict__ Vt_g,
                                             __bf16* __restrict__ O) {
    __shared__ __align__(16) __bf16 Ks[32][136];
    __shared__ __align__(16) __bf16 Vt[144][40];
    __shared__ __align__(16) __bf16 Ps[4][32][40];

    const int t = threadIdx.x, lane = t & 63, wave = t >> 6;
    const int fr = lane & 15, fq = lane >> 4;

    const int n = blockIdx.x + (int)gridDim.x * blockIdx.y;   // 0..511
    const int by = (n & 7) * 4 + (n >> 7);                    // b*16+h, 0..31
    const int bx = (n >> 3) & 15;                             // q-block, 0..15
    const int b = by >> 4, h = by & 15;

    const size_t baseQ = (size_t)b * S_LEN * 2048 + h * 128;
    const size_t baseV = (size_t)b * 2048 * 2048 + (size_t)h * 128 * 2048;
    const int q0 = bx * 128 + wave * 32;
    const float sc2 = 0.08838834764831845f * 1.4426950408889634f;  // (1/sqrt(128))*log2e
    const float M2 = 12.0f * 1.4426950408889634f;

    for (int idx = t; idx < 16 * 40; idx += 256) {
        const int rr = idx / 40, cc = idx - rr * 40;
        Vt[128 + rr][cc] = (rr == 0) ? (__bf16)1.0f : (__bf16)0.0f;
    }

    bf16x8 qf[2][4];
    for (int i2 = 0; i2 < 2; i2++) {
        const __bf16* qp = Q + baseQ + (size_t)(q0 + i2 * 16 + fr) * 2048 + fq * 8;
        for (int c = 0; c < 4; c++) qf[i2][c] = *(const bf16x8*)(qp + c * 32);
    }

    floatx4 oa[2][9] = {};

    const __bf16* Kp = K + baseQ + (size_t)(t >> 3) * 2048 + (t & 7) * 16;
    const __bf16* Vp = Vt_g + baseV + (size_t)(t >> 1) * 2048 + (t & 1) * 16;

    for (int kv0 = 0; kv0 < S_LEN; kv0 += 32) {
        *(uint4*)&Ks[t >> 3][(t & 7) * 16]     = *(const uint4*)(Kp);
        *(uint4*)&Ks[t >> 3][(t & 7) * 16 + 8] = *(const uint4*)(Kp + 8);
        *(uint4*)&Vt[t >> 1][(t & 1) * 16]     = *(const uint4*)(Vp);
        *(uint4*)&Vt[t >> 1][(t & 1) * 16 + 8] = *(const uint4*)(Vp + 8);
        Kp += (size_t)32 * 2048;
        Vp += 32;
        __syncthreads();

        floatx4 sacc[2][2] = {};
        __builtin_amdgcn_s_setprio(1);
        for (int c = 0; c < 4; c++) {
            const bf16x8 kf0 = *(const bf16x8*)&Ks[fr][c * 32 + fq * 8];
            const bf16x8 kf1 = *(const bf16x8*)&Ks[fr + 16][c * 32 + fq * 8];
            sacc[0][0] = __builtin_amdgcn_mfma_f32_16x16x32_bf16(qf[0][c], kf0, sacc[0][0], 0, 0, 0);
            sacc[0][1] = __builtin_amdgcn_mfma_f32_16x16x32_bf16(qf[0][c], kf1, sacc[0][1], 0, 0, 0);
            sacc[1][0] = __builtin_amdgcn_mfma_f32_16x16x32_bf16(qf[1][c], kf0, sacc[1][0], 0, 0, 0);
            sacc[1][1] = __builtin_amdgcn_mfma_f32_16x16x32_bf16(qf[1][c], kf1, sacc[1][1], 0, 0, 0);
        }
        __builtin_amdgcn_s_setprio(0);

        for (int i2 = 0; i2 < 2; i2++)
            for (int r = 0; r < 4; r++) {
                const int row = i2 * 16 + fq * 4 + r;
                Ps[wave][row][fr]      = (__bf16)exp2f(fmaf(sc2, sacc[i2][0][r], -M2));
                Ps[wave][row][fr + 16] = (__bf16)exp2f(fmaf(sc2, sacc[i2][1][r], -M2));
            }

        const bf16x8 pf0 = *(const bf16x8*)&Ps[wave][fr][fq * 8];
        const bf16x8 pf1 = *(const bf16x8*)&Ps[wave][16 + fr][fq * 8];
        __builtin_amdgcn_s_setprio(1);
        for (int nb = 0; nb < 9; nb++) {
            const bf16x8 vf = *(const bf16x8*)&Vt[nb * 16 + fr][fq * 8];
            oa[0][nb] = __builtin_amdgcn_mfma_f32_16x16x32_bf16(pf0, vf, oa[0][nb], 0, 0, 0);
            oa[1][nb] = __builtin_amdgcn_mfma_f32_16x16x32_bf16(pf1, vf, oa[1][nb], 0, 0, 0);
        }
        __builtin_amdgcn_s_setprio(0);
        __syncthreads();
    }

    for (int i2 = 0; i2 < 2; i2++)
        for (int r = 0; r < 4; r++) {
            float l = oa[i2][8][r];
            l = __shfl(l, fq * 16);
            const float inv = 1.0f / l;
            __bf16* op = O + baseQ + (size_t)(q0 + i2 * 16 + fq * 4 + r) * 2048;
            for (int nb = 0; nb < 8; nb++)
                op[nb * 16 + fr] = (__bf16)(oa[i2][nb][r] * inv);
        }
}

// ---------------------------------------------------------------------------
extern "C" void kernel_launch(void* const* d_in, const int* in_sizes, int n_in,
                              void* d_out, int out_size, void* d_ws, size_t ws_size,
                              hipStream_t stream) {
    const float* x    = (const float*)d_in[0];
    const float* rope = (const float*)d_in[1];
    const float* wq   = (const float*)d_in[2];
    const float* wk   = (const float*)d_in[3];
    const float* wv   = (const float*)d_in[4];
    const float* wo   = (const float*)d_in[5];
    const float* qnw  = (const float*)d_in[6];
    const float* knw  = (const float*)d_in[7];
    float* out = (float*)d_out;

    const size_t NTOK = 2 * 2048;
    const size_t ELEMS = NTOK * 2048;            // 8388608
    __bf16* xb  = (__bf16*)d_ws;                 // 16 MB; reused as ob after flash
    __bf16* qb  = xb + ELEMS;                    // 16 MB; reused for wo_bf after flash
    __bf16* kb  = qb + ELEMS;
    __bf16* vbT = kb + ELEMS;
    __bf16* ob  = xb;
    // d_out (32 MB fp32) doubles as scratch for the concatenated bf16 QKV
    // weights (25.2 MB) — fully consumed by gemm_qkv before gemm_out writes it.
    __bf16* wqkv = (__bf16*)d_out;
    __bf16* wob  = qb;                           // wo bf16 (8 MB), written after flash

    cvt_bf16<<<(int)(ELEMS / 4) / 256, 256, 0, stream>>>(x, xb, (int)(ELEMS / 4));
    cvt3_bf16<<<3 * (2048 * 2048 / 4) / 256, 256, 0, stream>>>(wq, wk, wv, wqkv);
    gemm_qkv<<<dim3(6144 / 256, (unsigned)(NTOK / 128)), 512, 98304, stream>>>(xb, wqkv, qb, kb, vbT);
    rmsrope<<<dim3((unsigned)(NTOK * 16 / 4), 2), 256, 0, stream>>>(qb, kb, rope, qnw, knw);
    flash<<<dim3(S_LEN / 128, 2 * 16), 256, 0, stream>>>(qb, kb, vbT, ob);
    cvt_bf16<<<(int)(2048 * 2048 / 4) / 256, 256, 0, stream>>>(wo, wob, 2048 * 2048 / 4);
    gemm_out<<<dim3(2048 / 256, (unsigned)(NTOK / 128)), 512, 98304, stream>>>(ob, wob, out);
}

// Round 4
// 445.412 us; speedup vs baseline: 1.0840x; 1.0840x over previous
//
#include <hip/hip_runtime.h>

typedef __bf16 bf16x8 __attribute__((ext_vector_type(8)));
typedef __bf16 bf16x4 __attribute__((ext_vector_type(4)));
typedef float floatx4 __attribute__((ext_vector_type(4)));

#define GK 2048
#define S_LEN 2048
#define NH 16
#define DH 128
#define NKT (GK / 64)

__device__ __forceinline__ void gl2lds16c(const __bf16* g, char* l) {
    __builtin_amdgcn_global_load_lds(
        (const __attribute__((address_space(1))) void*)g,
        (__attribute__((address_space(3))) void*)l, 16, 0, 0);
}

// ---------------------------------------------------------------------------
// fp32 -> bf16 bulk convert (one float4 -> bf16x4 per thread)
// ---------------------------------------------------------------------------
__global__ __launch_bounds__(256) void cvt_bf16(const float* __restrict__ in,
                                                __bf16* __restrict__ out, int n4) {
    int i = blockIdx.x * 256 + threadIdx.x;
    if (i < n4) {
        const float4 v = ((const float4*)in)[i];
        bf16x4 h;
        h[0] = (__bf16)v.x; h[1] = (__bf16)v.y; h[2] = (__bf16)v.z; h[3] = (__bf16)v.w;
        ((bf16x4*)out)[i] = h;
    }
}

// concat-convert wq|wk|wv (each 2048x2048 fp32) -> one bf16 [6144][2048]
__global__ __launch_bounds__(256) void cvt3_bf16(const float* __restrict__ a,
                                                 const float* __restrict__ b,
                                                 const float* __restrict__ c,
                                                 __bf16* __restrict__ out) {
    const int per = 2048 * 2048 / 4;
    int i = blockIdx.x * 256 + threadIdx.x;      // 0 .. 3*per-1
    const float* src = a; int j = i;
    if (i >= 2 * per)      { src = c; j = i - 2 * per; }
    else if (i >= per)     { src = b; j = i - per; }
    const float4 v = ((const float4*)src)[j];
    bf16x4 h;
    h[0] = (__bf16)v.x; h[1] = (__bf16)v.y; h[2] = (__bf16)v.z; h[3] = (__bf16)v.w;
    ((bf16x4*)out)[i] = h;
}

// XCD-aware bijective remap of a linear block id (nwg must be %8==0).
__device__ __forceinline__ int xcd_remap(int L, int nwg) {
    return (L & 7) * (nwg >> 3) + (L >> 3);
}

// ---------------------------------------------------------------------------
// 4-phase-per-K-tile 256x256 GEMM body: C[m][n] = sum_k A[m][k] * W[n][k].
// BK=64, 8 waves (2m x 4n), per-wave 128x64 out (acc[8][4]).
// LDS: 2 buffers x (A 256x64 + B 256x64) = 128 KB, row stride 128B,
//      element (r,c) at byte r*128 + (2c ^ ((r&7)<<4))   [T2 swizzle]
// Staged via global_load_lds (linear dest) from pre-swizzled global cols.
// Region lifetimes (buffer p = t&1, staging tile t+2 into the SAME p):
//   A-slice q (rows q*64) read ONLY in phase q  -> dead after phase q barrier
//   B read into regs in phase 0                 -> dead after phase 0 barrier
// Issue: ph1: A0+B0+B1, ph2: A1+B2+B3, ph3: A2, boundary: A3 (8 loads/thr/tile)
// Entry wait: vmcnt(8) = exactly this tile's 8 loads (next tile's stay in
// flight across all phase barriers); vmcnt(0) only on the peeled last tile.
// ---------------------------------------------------------------------------
__device__ __forceinline__ void gemm_body3(const __bf16* __restrict__ A,
                                           const __bf16* __restrict__ W,
                                           int m0, int n0, char* lds,
                                           floatx4 (*acc)[4]) {
    const int t = threadIdx.x, l = t & 63, wave = t >> 6;
    const int fr = l & 15, fq = l >> 4;
    const int wm = wave >> 2, wn = wave & 3;

    // pre-swizzled global column so linear LDS writes land swizzled (rule 21)
    const int swcol = ((l & 7) * 8) ^ (((l >> 3) & 7) * 8);
    const __bf16* gA = A + (size_t)(m0 + wave * 8 + (l >> 3)) * GK + swcol;
    const __bf16* gW = W + (size_t)(n0 + wave * 8 + (l >> 3)) * GK + swcol;
    char* const ldsW = lds + wave * 1024;   // wave-uniform dest base

    auto stageA = [&](int p, int kt, int q) {   // one 64-row A slice
        gl2lds16c(gA + (size_t)q * 64 * GK + kt * 64,
                  ldsW + p * 65536 + q * 8192);
    };
    auto stageBh = [&](int p, int kt, int h) {  // one 64-row B slice
        gl2lds16c(gW + (size_t)h * 64 * GK + kt * 64,
                  ldsW + p * 65536 + 32768 + h * 8192);
    };

    // prologue: tiles 0 and 1 fully staged (8 loads each)
#pragma unroll
    for (int q = 0; q < 4; q++) stageA(0, 0, q);
#pragma unroll
    for (int h = 0; h < 4; h++) stageBh(0, 0, h);
#pragma unroll
    for (int q = 0; q < 4; q++) stageA(1, 1, q);
#pragma unroll
    for (int h = 0; h < 4; h++) stageBh(1, 1, h);

    const int sw = (fr & 7) << 4;
    const int cb0 = (fq * 16) ^ sw;          // k-slot 0 byte offset in row
    const int cb1 = (64 + fq * 16) ^ sw;     // k-slot 1

    for (int t0 = 0; t0 < NKT; t0++) {
        const int p = t0 & 1;
        if (t0 == NKT - 1) { asm volatile("s_waitcnt vmcnt(0)" ::: "memory"); }
        else               { asm volatile("s_waitcnt vmcnt(8)" ::: "memory"); }
        __builtin_amdgcn_s_barrier();        // all waves passed their vmcnt
        asm volatile("" ::: "memory");

        const char* bufA = lds + p * 65536;
        const char* bufB = bufA + 32768;

        // B fragments for the whole tile (held in regs; B region dead after ph0)
        bf16x8 bB[4][2];
#pragma unroll
        for (int j = 0; j < 4; j++) {
            const char* rb = bufB + (wn * 64 + j * 16 + fr) * 128;
            bB[j][0] = *(const bf16x8*)(rb + cb0);
            bB[j][1] = *(const bf16x8*)(rb + cb1);
        }

#pragma unroll
        for (int q = 0; q < 4; q++) {
            if (t0 + 2 < NKT) {   // staging into regions certified dead
                if (q == 1) { stageA(p, t0 + 2, 0); stageBh(p, t0 + 2, 0); stageBh(p, t0 + 2, 1); }
                if (q == 2) { stageA(p, t0 + 2, 1); stageBh(p, t0 + 2, 2); stageBh(p, t0 + 2, 3); }
                if (q == 3) { stageA(p, t0 + 2, 2); }
            }
            const char* ra = bufA + (q * 64 + wm * 32 + fr) * 128;
            bf16x8 bA[2][2];
#pragma unroll
            for (int i = 0; i < 2; i++) {
                bA[i][0] = *(const bf16x8*)(ra + i * 2048 + cb0);
                bA[i][1] = *(const bf16x8*)(ra + i * 2048 + cb1);
            }
            __builtin_amdgcn_s_setprio(1);
#pragma unroll
            for (int i = 0; i < 2; i++)
#pragma unroll
                for (int j = 0; j < 4; j++) {
                    acc[2 * q + i][j] = __builtin_amdgcn_mfma_f32_16x16x32_bf16(bA[i][0], bB[j][0], acc[2 * q + i][j], 0, 0, 0);
                    acc[2 * q + i][j] = __builtin_amdgcn_mfma_f32_16x16x32_bf16(bA[i][1], bB[j][1], acc[2 * q + i][j], 0, 0, 0);
                }
            __builtin_amdgcn_s_setprio(0);
            __builtin_amdgcn_s_barrier();    // phase q region now dead
            asm volatile("" ::: "memory");
        }
        if (t0 + 2 < NKT) stageA(p, t0 + 2, 3);   // A3 dead after ph3 barrier
    }
}

// Fused QKV projection: A (4096x2048 bf16) x Wqkv (6144x2048 bf16).
// n<2048 -> qb, n<4096 -> kb (row-major [b*S][2048]); n>=4096 -> vbT
// ([b][h*128+d][s], transposed for flash staging). 256-tiles never straddle.
__global__ __launch_bounds__(512, 2) void gemm_qkv(const __bf16* __restrict__ A,
                                                   const __bf16* __restrict__ W,
                                                   __bf16* __restrict__ qb,
                                                   __bf16* __restrict__ kb,
                                                   __bf16* __restrict__ vbT) {
    extern __shared__ __align__(16) char lds[];
    const int gx = gridDim.x;                         // 24
    const int L = blockIdx.x + gx * blockIdx.y;
    const int tid2 = xcd_remap(L, gx * (int)gridDim.y);
    const int m0 = (tid2 / gx) * 256, n0 = (tid2 % gx) * 256;
    floatx4 acc[8][4] = {};
    gemm_body3(A, W, m0, n0, lds, acc);

    const int lane = threadIdx.x & 63, wave = threadIdx.x >> 6;
    const int fr = lane & 15, fq = lane >> 4;
    const int wm = wave >> 2, wn = wave & 3;
    const int which = n0 >> 11;          // 0=q 1=k 2=v (block-uniform, 256|2048)
    const int nc0 = n0 & 2047;

    for (int mi = 0; mi < 8; mi++)
        for (int j = 0; j < 4; j++) {
            const int row = m0 + (mi >> 1) * 64 + wm * 32 + (mi & 1) * 16 + fq * 4;
            const int col = nc0 + wn * 64 + j * 16 + fr;
            if (which == 2) {
                // vbT[b][col][s]; b = row>>11, s = row&2047 (row%4==0 -> 8B aligned)
                __bf16* Cp = vbT + (((size_t)(row & ~2047)) << 11) +
                             (size_t)col * 2048 + (row & 2047);
                bf16x4 hv;
                for (int r = 0; r < 4; r++) hv[r] = (__bf16)acc[mi][j][r];
                *(bf16x4*)Cp = hv;
            } else {
                __bf16* dst = which ? kb : qb;
                for (int r = 0; r < 4; r++)
                    dst[(size_t)(row + r) * 2048 + col] = (__bf16)acc[mi][j][r];
            }
        }
}

// Out-projection: A (4096x2048 bf16) x Wo (2048x2048 bf16) -> fp32 out
__global__ __launch_bounds__(512, 2) void gemm_out(const __bf16* __restrict__ A,
                                                   const __bf16* __restrict__ W,
                                                   float* __restrict__ C) {
    extern __shared__ __align__(16) char lds[];
    const int gx = gridDim.x;                         // 8
    const int L = blockIdx.x + gx * blockIdx.y;
    const int tid2 = xcd_remap(L, gx * (int)gridDim.y);
    const int m0 = (tid2 / gx) * 256, n0 = (tid2 % gx) * 256;
    floatx4 acc[8][4] = {};
    gemm_body3(A, W, m0, n0, lds, acc);

    const int lane = threadIdx.x & 63, wave = threadIdx.x >> 6;
    const int fr = lane & 15, fq = lane >> 4;
    const int wm = wave >> 2, wn = wave & 3;
    for (int mi = 0; mi < 8; mi++)
        for (int j = 0; j < 4; j++) {
            const int row = m0 + (mi >> 1) * 64 + wm * 32 + (mi & 1) * 16 + fq * 4;
            const int col = n0 + wn * 64 + j * 16 + fr;
            for (int r = 0; r < 4; r++)
                C[(size_t)(row + r) * 2048 + col] = acc[mi][j][r];
        }
}

// ---------------------------------------------------------------------------
// Fused RMSNorm (per head, DH=128, fp32 math) + RoPE, in-place on bf16 q/k.
// ---------------------------------------------------------------------------
__global__ __launch_bounds__(256) void rmsrope(__bf16* __restrict__ qb,
                                               __bf16* __restrict__ kb,
                                               const float* __restrict__ rope,
                                               const float* __restrict__ qw,
                                               const float* __restrict__ kw) {
    const int lane = threadIdx.x & 63;
    const int row = blockIdx.x * 4 + (threadIdx.x >> 6);   // (b*S + s)*H + h
    __bf16* p = (blockIdx.y ? kb : qb) + (size_t)row * DH;
    const float* w = blockIdx.y ? kw : qw;
    const int s = (row >> 4) & (S_LEN - 1);

    float t0 = (float)p[lane];
    float t1 = (float)p[lane + 64];
    float ss = t0 * t0 + t1 * t1;
    for (int o = 32; o; o >>= 1) ss += __shfl_xor(ss, o, 64);
    const float inv = rsqrtf(ss * (1.0f / 128.0f) + 1e-6f);
    t0 *= inv * w[lane];
    t1 *= inv * w[lane + 64];

    const float4 f = *(const float4*)(rope + (size_t)s * 256 + lane * 4);
    p[lane]      = (__bf16)(f.x * t0 + f.y * t1);
    p[lane + 64] = (__bf16)(f.z * t0 + f.w * t1);
}

// ---------------------------------------------------------------------------
// Flash attention (round-2 version, unchanged): fixed-max softmax
// (p = exp2(s*sc*log2e - M2)), l via MFMA ones-column.
// grid = (S/128, B*H), 4 waves x 32 q-rows, KV tile 32.
// XCD remap: all 16 q-blocks of 4 heads share one XCD -> K/V (4 MB) lives in
// that XCD's L2 (round-1 evidence: FETCH 139 MB -> 33 MB).
// ---------------------------------------------------------------------------
__global__ __launch_bounds__(256) void flash(const __bf16* __restrict__ Q,
                                             const __bf16* __restrict__ K,
                                             const __bf16* __restrict__ Vt_g,
                                             __bf16* __restrict__ O) {
    __shared__ __align__(16) __bf16 Ks[32][136];
    __shared__ __align__(16) __bf16 Vt[144][40];
    __shared__ __align__(16) __bf16 Ps[4][32][40];

    const int t = threadIdx.x, lane = t & 63, wave = t >> 6;
    const int fr = lane & 15, fq = lane >> 4;

    const int n = blockIdx.x + (int)gridDim.x * blockIdx.y;   // 0..511
    const int by = (n & 7) * 4 + (n >> 7);                    // b*16+h, 0..31
    const int bx = (n >> 3) & 15;                             // q-block, 0..15
    const int b = by >> 4, h = by & 15;

    const size_t baseQ = (size_t)b * S_LEN * 2048 + h * 128;
    const size_t baseV = (size_t)b * 2048 * 2048 + (size_t)h * 128 * 2048;
    const int q0 = bx * 128 + wave * 32;
    const float sc2 = 0.08838834764831845f * 1.4426950408889634f;  // (1/sqrt(128))*log2e
    const float M2 = 12.0f * 1.4426950408889634f;

    for (int idx = t; idx < 16 * 40; idx += 256) {
        const int rr = idx / 40, cc = idx - rr * 40;
        Vt[128 + rr][cc] = (rr == 0) ? (__bf16)1.0f : (__bf16)0.0f;
    }

    bf16x8 qf[2][4];
    for (int i2 = 0; i2 < 2; i2++) {
        const __bf16* qp = Q + baseQ + (size_t)(q0 + i2 * 16 + fr) * 2048 + fq * 8;
        for (int c = 0; c < 4; c++) qf[i2][c] = *(const bf16x8*)(qp + c * 32);
    }

    floatx4 oa[2][9] = {};

    const __bf16* Kp = K + baseQ + (size_t)(t >> 3) * 2048 + (t & 7) * 16;
    const __bf16* Vp = Vt_g + baseV + (size_t)(t >> 1) * 2048 + (t & 1) * 16;

    for (int kv0 = 0; kv0 < S_LEN; kv0 += 32) {
        *(uint4*)&Ks[t >> 3][(t & 7) * 16]     = *(const uint4*)(Kp);
        *(uint4*)&Ks[t >> 3][(t & 7) * 16 + 8] = *(const uint4*)(Kp + 8);
        *(uint4*)&Vt[t >> 1][(t & 1) * 16]     = *(const uint4*)(Vp);
        *(uint4*)&Vt[t >> 1][(t & 1) * 16 + 8] = *(const uint4*)(Vp + 8);
        Kp += (size_t)32 * 2048;
        Vp += 32;
        __syncthreads();

        floatx4 sacc[2][2] = {};
        __builtin_amdgcn_s_setprio(1);
        for (int c = 0; c < 4; c++) {
            const bf16x8 kf0 = *(const bf16x8*)&Ks[fr][c * 32 + fq * 8];
            const bf16x8 kf1 = *(const bf16x8*)&Ks[fr + 16][c * 32 + fq * 8];
            sacc[0][0] = __builtin_amdgcn_mfma_f32_16x16x32_bf16(qf[0][c], kf0, sacc[0][0], 0, 0, 0);
            sacc[0][1] = __builtin_amdgcn_mfma_f32_16x16x32_bf16(qf[0][c], kf1, sacc[0][1], 0, 0, 0);
            sacc[1][0] = __builtin_amdgcn_mfma_f32_16x16x32_bf16(qf[1][c], kf0, sacc[1][0], 0, 0, 0);
            sacc[1][1] = __builtin_amdgcn_mfma_f32_16x16x32_bf16(qf[1][c], kf1, sacc[1][1], 0, 0, 0);
        }
        __builtin_amdgcn_s_setprio(0);

        for (int i2 = 0; i2 < 2; i2++)
            for (int r = 0; r < 4; r++) {
                const int row = i2 * 16 + fq * 4 + r;
                Ps[wave][row][fr]      = (__bf16)exp2f(fmaf(sc2, sacc[i2][0][r], -M2));
                Ps[wave][row][fr + 16] = (__bf16)exp2f(fmaf(sc2, sacc[i2][1][r], -M2));
            }

        const bf16x8 pf0 = *(const bf16x8*)&Ps[wave][fr][fq * 8];
        const bf16x8 pf1 = *(const bf16x8*)&Ps[wave][16 + fr][fq * 8];
        __builtin_amdgcn_s_setprio(1);
        for (int nb = 0; nb < 9; nb++) {
            const bf16x8 vf = *(const bf16x8*)&Vt[nb * 16 + fr][fq * 8];
            oa[0][nb] = __builtin_amdgcn_mfma_f32_16x16x32_bf16(pf0, vf, oa[0][nb], 0, 0, 0);
            oa[1][nb] = __builtin_amdgcn_mfma_f32_16x16x32_bf16(pf1, vf, oa[1][nb], 0, 0, 0);
        }
        __builtin_amdgcn_s_setprio(0);
        __syncthreads();
    }

    for (int i2 = 0; i2 < 2; i2++)
        for (int r = 0; r < 4; r++) {
            float l = oa[i2][8][r];
            l = __shfl(l, fq * 16);
            const float inv = 1.0f / l;
            __bf16* op = O + baseQ + (size_t)(q0 + i2 * 16 + fq * 4 + r) * 2048;
            for (int nb = 0; nb < 8; nb++)
                op[nb * 16 + fr] = (__bf16)(oa[i2][nb][r] * inv);
        }
}

// ---------------------------------------------------------------------------
extern "C" void kernel_launch(void* const* d_in, const int* in_sizes, int n_in,
                              void* d_out, int out_size, void* d_ws, size_t ws_size,
                              hipStream_t stream) {
    const float* x    = (const float*)d_in[0];
    const float* rope = (const float*)d_in[1];
    const float* wq   = (const float*)d_in[2];
    const float* wk   = (const float*)d_in[3];
    const float* wv   = (const float*)d_in[4];
    const float* wo   = (const float*)d_in[5];
    const float* qnw  = (const float*)d_in[6];
    const float* knw  = (const float*)d_in[7];
    float* out = (float*)d_out;

    static bool attr_set = false;
    if (!attr_set) {
        hipFuncSetAttribute((const void*)gemm_qkv,
                            hipFuncAttributeMaxDynamicSharedMemorySize, 131072);
        hipFuncSetAttribute((const void*)gemm_out,
                            hipFuncAttributeMaxDynamicSharedMemorySize, 131072);
        attr_set = true;
    }

    const size_t NTOK = 2 * 2048;
    const size_t ELEMS = NTOK * 2048;            // 8388608
    __bf16* xb  = (__bf16*)d_ws;                 // 16 MB; reused as ob after flash
    __bf16* qb  = xb + ELEMS;                    // 16 MB; reused for wo_bf after flash
    __bf16* kb  = qb + ELEMS;
    __bf16* vbT = kb + ELEMS;
    __bf16* ob  = xb;
    // d_out (32 MB fp32) doubles as scratch for the concatenated bf16 QKV
    // weights (25.2 MB) — fully consumed by gemm_qkv before gemm_out writes it.
    __bf16* wqkv = (__bf16*)d_out;
    __bf16* wob  = qb;                           // wo bf16 (8 MB), written after flash

    cvt_bf16<<<(int)(ELEMS / 4) / 256, 256, 0, stream>>>(x, xb, (int)(ELEMS / 4));
    cvt3_bf16<<<3 * (2048 * 2048 / 4) / 256, 256, 0, stream>>>(wq, wk, wv, wqkv);
    gemm_qkv<<<dim3(6144 / 256, (unsigned)(NTOK / 256)), 512, 131072, stream>>>(xb, wqkv, qb, kb, vbT);
    rmsrope<<<dim3((unsigned)(NTOK * 16 / 4), 2), 256, 0, stream>>>(qb, kb, rope, qnw, knw);
    flash<<<dim3(S_LEN / 128, 2 * 16), 256, 0, stream>>>(qb, kb, vbT, ob);
    cvt_bf16<<<(int)(2048 * 2048 / 4) / 256, 256, 0, stream>>>(wo, wob, 2048 * 2048 / 4);
    gemm_out<<<dim3(2048 / 256, (unsigned)(NTOK / 256)), 512, 131072, stream>>>(ob, wob, out);
}

// Round 5
// 411.235 us; speedup vs baseline: 1.1741x; 1.0831x over previous
//
#include <hip/hip_runtime.h>

typedef __bf16 bf16x8 __attribute__((ext_vector_type(8)));
typedef __bf16 bf16x4 __attribute__((ext_vector_type(4)));
typedef float floatx4 __attribute__((ext_vector_type(4)));

#define GK 2048
#define S_LEN 2048
#define NH 16
#define DH 128
#define NKT (GK / 64)

__device__ __forceinline__ void gl2lds16c(const __bf16* g, char* l) {
    __builtin_amdgcn_global_load_lds(
        (const __attribute__((address_space(1))) void*)g,
        (__attribute__((address_space(3))) void*)l, 16, 0, 0);
}

// ---------------------------------------------------------------------------
// fp32 -> bf16 bulk convert (one float4 -> bf16x4 per thread)
// ---------------------------------------------------------------------------
__global__ __launch_bounds__(256) void cvt_bf16(const float* __restrict__ in,
                                                __bf16* __restrict__ out, int n4) {
    int i = blockIdx.x * 256 + threadIdx.x;
    if (i < n4) {
        const float4 v = ((const float4*)in)[i];
        bf16x4 h;
        h[0] = (__bf16)v.x; h[1] = (__bf16)v.y; h[2] = (__bf16)v.z; h[3] = (__bf16)v.w;
        ((bf16x4*)out)[i] = h;
    }
}

// concat-convert wq|wk|wv (each 2048x2048 fp32) -> one bf16 [6144][2048]
__global__ __launch_bounds__(256) void cvt3_bf16(const float* __restrict__ a,
                                                 const float* __restrict__ b,
                                                 const float* __restrict__ c,
                                                 __bf16* __restrict__ out) {
    const int per = 2048 * 2048 / 4;
    int i = blockIdx.x * 256 + threadIdx.x;      // 0 .. 3*per-1
    const float* src = a; int j = i;
    if (i >= 2 * per)      { src = c; j = i - 2 * per; }
    else if (i >= per)     { src = b; j = i - per; }
    const float4 v = ((const float4*)src)[j];
    bf16x4 h;
    h[0] = (__bf16)v.x; h[1] = (__bf16)v.y; h[2] = (__bf16)v.z; h[3] = (__bf16)v.w;
    ((bf16x4*)out)[i] = h;
}

// XCD-aware bijective remap of a linear block id (nwg must be %8==0).
__device__ __forceinline__ int xcd_remap(int L, int nwg) {
    return (L & 7) * (nwg >> 3) + (L >> 3);
}

// ---------------------------------------------------------------------------
// 4-phase-per-K-tile 256x256 GEMM body (validated round 4).
// ---------------------------------------------------------------------------
__device__ __forceinline__ void gemm_body3(const __bf16* __restrict__ A,
                                           const __bf16* __restrict__ W,
                                           int m0, int n0, char* lds,
                                           floatx4 (*acc)[4]) {
    const int t = threadIdx.x, l = t & 63, wave = t >> 6;
    const int fr = l & 15, fq = l >> 4;
    const int wm = wave >> 2, wn = wave & 3;

    const int swcol = ((l & 7) * 8) ^ (((l >> 3) & 7) * 8);
    const __bf16* gA = A + (size_t)(m0 + wave * 8 + (l >> 3)) * GK + swcol;
    const __bf16* gW = W + (size_t)(n0 + wave * 8 + (l >> 3)) * GK + swcol;
    char* const ldsW = lds + wave * 1024;

    auto stageA = [&](int p, int kt, int q) {
        gl2lds16c(gA + (size_t)q * 64 * GK + kt * 64,
                  ldsW + p * 65536 + q * 8192);
    };
    auto stageBh = [&](int p, int kt, int h) {
        gl2lds16c(gW + (size_t)h * 64 * GK + kt * 64,
                  ldsW + p * 65536 + 32768 + h * 8192);
    };

#pragma unroll
    for (int q = 0; q < 4; q++) stageA(0, 0, q);
#pragma unroll
    for (int h = 0; h < 4; h++) stageBh(0, 0, h);
#pragma unroll
    for (int q = 0; q < 4; q++) stageA(1, 1, q);
#pragma unroll
    for (int h = 0; h < 4; h++) stageBh(1, 1, h);

    const int sw = (fr & 7) << 4;
    const int cb0 = (fq * 16) ^ sw;
    const int cb1 = (64 + fq * 16) ^ sw;

    for (int t0 = 0; t0 < NKT; t0++) {
        const int p = t0 & 1;
        if (t0 == NKT - 1) { asm volatile("s_waitcnt vmcnt(0)" ::: "memory"); }
        else               { asm volatile("s_waitcnt vmcnt(8)" ::: "memory"); }
        __builtin_amdgcn_s_barrier();
        asm volatile("" ::: "memory");

        const char* bufA = lds + p * 65536;
        const char* bufB = bufA + 32768;

        bf16x8 bB[4][2];
#pragma unroll
        for (int j = 0; j < 4; j++) {
            const char* rb = bufB + (wn * 64 + j * 16 + fr) * 128;
            bB[j][0] = *(const bf16x8*)(rb + cb0);
            bB[j][1] = *(const bf16x8*)(rb + cb1);
        }

#pragma unroll
        for (int q = 0; q < 4; q++) {
            if (t0 + 2 < NKT) {
                if (q == 1) { stageA(p, t0 + 2, 0); stageBh(p, t0 + 2, 0); stageBh(p, t0 + 2, 1); }
                if (q == 2) { stageA(p, t0 + 2, 1); stageBh(p, t0 + 2, 2); stageBh(p, t0 + 2, 3); }
                if (q == 3) { stageA(p, t0 + 2, 2); }
            }
            const char* ra = bufA + (q * 64 + wm * 32 + fr) * 128;
            bf16x8 bA[2][2];
#pragma unroll
            for (int i = 0; i < 2; i++) {
                bA[i][0] = *(const bf16x8*)(ra + i * 2048 + cb0);
                bA[i][1] = *(const bf16x8*)(ra + i * 2048 + cb1);
            }
            __builtin_amdgcn_s_setprio(1);
#pragma unroll
            for (int i = 0; i < 2; i++)
#pragma unroll
                for (int j = 0; j < 4; j++) {
                    acc[2 * q + i][j] = __builtin_amdgcn_mfma_f32_16x16x32_bf16(bA[i][0], bB[j][0], acc[2 * q + i][j], 0, 0, 0);
                    acc[2 * q + i][j] = __builtin_amdgcn_mfma_f32_16x16x32_bf16(bA[i][1], bB[j][1], acc[2 * q + i][j], 0, 0, 0);
                }
            __builtin_amdgcn_s_setprio(0);
            __builtin_amdgcn_s_barrier();
            asm volatile("" ::: "memory");
        }
        if (t0 + 2 < NKT) stageA(p, t0 + 2, 3);
    }
}

// Fused QKV projection (round-4 version, validated).
__global__ __launch_bounds__(512, 2) void gemm_qkv(const __bf16* __restrict__ A,
                                                   const __bf16* __restrict__ W,
                                                   __bf16* __restrict__ qb,
                                                   __bf16* __restrict__ kb,
                                                   __bf16* __restrict__ vbT) {
    extern __shared__ __align__(16) char lds[];
    const int gx = gridDim.x;                         // 24
    const int L = blockIdx.x + gx * blockIdx.y;
    const int tid2 = xcd_remap(L, gx * (int)gridDim.y);
    const int m0 = (tid2 / gx) * 256, n0 = (tid2 % gx) * 256;
    floatx4 acc[8][4] = {};
    gemm_body3(A, W, m0, n0, lds, acc);

    const int lane = threadIdx.x & 63, wave = threadIdx.x >> 6;
    const int fr = lane & 15, fq = lane >> 4;
    const int wm = wave >> 2, wn = wave & 3;
    const int which = n0 >> 11;
    const int nc0 = n0 & 2047;

    for (int mi = 0; mi < 8; mi++)
        for (int j = 0; j < 4; j++) {
            const int row = m0 + (mi >> 1) * 64 + wm * 32 + (mi & 1) * 16 + fq * 4;
            const int col = nc0 + wn * 64 + j * 16 + fr;
            if (which == 2) {
                __bf16* Cp = vbT + (((size_t)(row & ~2047)) << 11) +
                             (size_t)col * 2048 + (row & 2047);
                bf16x4 hv;
                for (int r = 0; r < 4; r++) hv[r] = (__bf16)acc[mi][j][r];
                *(bf16x4*)Cp = hv;
            } else {
                __bf16* dst = which ? kb : qb;
                for (int r = 0; r < 4; r++)
                    dst[(size_t)(row + r) * 2048 + col] = (__bf16)acc[mi][j][r];
            }
        }
}

// Out-projection (round-4 version, validated).
__global__ __launch_bounds__(512, 2) void gemm_out(const __bf16* __restrict__ A,
                                                   const __bf16* __restrict__ W,
                                                   float* __restrict__ C) {
    extern __shared__ __align__(16) char lds[];
    const int gx = gridDim.x;                         // 8
    const int L = blockIdx.x + gx * blockIdx.y;
    const int tid2 = xcd_remap(L, gx * (int)gridDim.y);
    const int m0 = (tid2 / gx) * 256, n0 = (tid2 % gx) * 256;
    floatx4 acc[8][4] = {};
    gemm_body3(A, W, m0, n0, lds, acc);

    const int lane = threadIdx.x & 63, wave = threadIdx.x >> 6;
    const int fr = lane & 15, fq = lane >> 4;
    const int wm = wave >> 2, wn = wave & 3;
    for (int mi = 0; mi < 8; mi++)
        for (int j = 0; j < 4; j++) {
            const int row = m0 + (mi >> 1) * 64 + wm * 32 + (mi & 1) * 16 + fq * 4;
            const int col = n0 + wn * 64 + j * 16 + fr;
            for (int r = 0; r < 4; r++)
                C[(size_t)(row + r) * 2048 + col] = acc[mi][j][r];
        }
}

// ---------------------------------------------------------------------------
// Fused RMSNorm (per head, DH=128, fp32 math) + RoPE, in-place on bf16 q/k.
// ---------------------------------------------------------------------------
__global__ __launch_bounds__(256) void rmsrope(__bf16* __restrict__ qb,
                                               __bf16* __restrict__ kb,
                                               const float* __restrict__ rope,
                                               const float* __restrict__ qw,
                                               const float* __restrict__ kw) {
    const int lane = threadIdx.x & 63;
    const int row = blockIdx.x * 4 + (threadIdx.x >> 6);   // (b*S + s)*H + h
    __bf16* p = (blockIdx.y ? kb : qb) + (size_t)row * DH;
    const float* w = blockIdx.y ? kw : qw;
    const int s = (row >> 4) & (S_LEN - 1);

    float t0 = (float)p[lane];
    float t1 = (float)p[lane + 64];
    float ss = t0 * t0 + t1 * t1;
    for (int o = 32; o; o >>= 1) ss += __shfl_xor(ss, o, 64);
    const float inv = rsqrtf(ss * (1.0f / 128.0f) + 1e-6f);
    t0 *= inv * w[lane];
    t1 *= inv * w[lane + 64];

    const float4 f = *(const float4*)(rope + (size_t)s * 256 + lane * 4);
    p[lane]      = (__bf16)(f.x * t0 + f.y * t1);
    p[lane + 64] = (__bf16)(f.z * t0 + f.w * t1);
}

// ---------------------------------------------------------------------------
// Flash attention v3: KVBLK=64, double-buffered K/V via global_load_lds with
// counted vmcnt(8) (gemm_body3 idiom), T2 XOR-swizzled LDS everywhere
// (rule 21: linear gl2lds dest + pre-swizzled GLOBAL source + swizzled read),
// fixed-max softmax p = exp2(s*sc*log2e - M2), l-sum via all-ones register
// B-fragment MFMA (no LDS ones rows, no epilogue shuffle).
// grid = (S/128, B*H), 4 waves x 32 q-rows. LDS = 80KB -> 2 blocks/CU.
//   [0,32K)  K dbuf: 2 x [64 kv][256B], elem(r,c) @ r*256 + (2c ^ ((r&7)<<4))
//   [32K,64K) V dbuf: 2 x [128 d][128B], elem(r,c) @ r*128 + (2c ^ ((r&7)<<4))
//   [64K,80K) Ps: per-wave [32 q][128B], same swizzle
// ---------------------------------------------------------------------------
__global__ __launch_bounds__(256, 2) void flash(const __bf16* __restrict__ Q,
                                                const __bf16* __restrict__ K,
                                                const __bf16* __restrict__ Vt_g,
                                                __bf16* __restrict__ O) {
    extern __shared__ __align__(16) char lds[];

    const int t = threadIdx.x, lane = t & 63, wave = t >> 6;
    const int fr = lane & 15, fq = lane >> 4;

    // T1 XCD remap: 16 q-blocks x 4 heads per XCD (K/V 4MB -> one L2)
    const int n = blockIdx.x + (int)gridDim.x * blockIdx.y;   // 0..511
    const int by = (n & 7) * 4 + (n >> 7);                    // b*16+h
    const int bx = (n >> 3) & 15;                             // q-block
    const int b = by >> 4, h = by & 15;

    const size_t baseQ = (size_t)b * S_LEN * 2048 + h * 128;
    const size_t baseV = (size_t)b * 2048 * 2048 + (size_t)h * 128 * 2048;
    const int q0 = bx * 128 + wave * 32;
    const float sc2 = 0.08838834764831845f * 1.4426950408889634f;  // (1/sqrt(128))*log2e
    const float M2 = 12.0f * 1.4426950408889634f;

    // Q fragments (regs, whole loop); fence so in-loop vmcnt counts only gl2lds
    bf16x8 qf[2][4];
#pragma unroll
    for (int i2 = 0; i2 < 2; i2++) {
        const __bf16* qp = Q + baseQ + (size_t)(q0 + i2 * 16 + fr) * 2048 + fq * 8;
#pragma unroll
        for (int c = 0; c < 4; c++) qf[i2][c] = *(const bf16x8*)(qp + c * 32);
    }
    asm volatile("s_waitcnt vmcnt(0)" ::: "memory");

    bf16x8 onesb;
#pragma unroll
    for (int e = 0; e < 8; e++) onesb[e] = (__bf16)1.0f;

    // staging geometry (pre-swizzled source columns)
    const int l4 = lane >> 4;            // K: row-in-4, chunk c16
    const int c16 = lane & 15;
    const int l3 = lane >> 3;            // V: row-in-8, chunk c8
    const int c8 = lane & 7;
    const __bf16* gK0 = K + baseQ + (size_t)(wave * 16 + l4) * 2048 + (c16 ^ l4) * 8;
    const __bf16* gK1 = K + baseQ + (size_t)(wave * 16 + l4) * 2048 + (c16 ^ (4 + l4)) * 8;
    const __bf16* gV  = Vt_g + baseV + (size_t)(wave * 8 + l3) * 2048 + (c8 ^ l3) * 8;

    char* const kdw = lds + wave * 4096;
    char* const vdw = lds + 32768 + wave * 1024;

    auto stage = [&](int p, int it2) {
        const size_t ko = (size_t)it2 * 64 * 2048;
        char* kd = kdw + p * 16384;
        gl2lds16c(gK0 + ko,                      kd);
        gl2lds16c(gK1 + ko + (size_t)4 * 2048,   kd + 1024);
        gl2lds16c(gK0 + ko + (size_t)8 * 2048,   kd + 2048);
        gl2lds16c(gK1 + ko + (size_t)12 * 2048,  kd + 3072);
        const __bf16* v = gV + it2 * 64;
        char* vd = vdw + p * 16384;
        gl2lds16c(v,                        vd);
        gl2lds16c(v + (size_t)32 * 2048,    vd + 4096);
        gl2lds16c(v + (size_t)64 * 2048,    vd + 8192);
        gl2lds16c(v + (size_t)96 * 2048,    vd + 12288);
    };

    stage(0, 0);
    stage(1, 1);

    floatx4 oa[2][9] = {};
    char* const Pw = lds + 65536 + wave * 4096;
    const int sw = (fr & 7) << 4;

    for (int it = 0; it < 32; ++it) {
        const int p = it & 1;
        if (it == 31) { asm volatile("s_waitcnt vmcnt(0)" ::: "memory"); }
        else          { asm volatile("s_waitcnt vmcnt(8)" ::: "memory"); }
        __builtin_amdgcn_s_barrier();
        asm volatile("" ::: "memory");

        const char* Kb = lds + p * 16384;
        const char* Vb = lds + 32768 + p * 16384;

        // ---- QK^T: sacc[i2][j] covers q-rows i2*16.., kv-cols j*16+fr ----
        floatx4 sacc[2][4] = {};
#pragma unroll
        for (int j = 0; j < 4; j++) {
            const char* kr = Kb + (j * 16 + fr) * 256;
            const bf16x8 kf0 = *(const bf16x8*)(kr + ((0 + fq * 16) ^ sw));
            const bf16x8 kf1 = *(const bf16x8*)(kr + ((64 + fq * 16) ^ sw));
            const bf16x8 kf2 = *(const bf16x8*)(kr + ((128 + fq * 16) ^ sw));
            const bf16x8 kf3 = *(const bf16x8*)(kr + ((192 + fq * 16) ^ sw));
            __builtin_amdgcn_s_setprio(1);
            sacc[0][j] = __builtin_amdgcn_mfma_f32_16x16x32_bf16(qf[0][0], kf0, sacc[0][j], 0, 0, 0);
            sacc[1][j] = __builtin_amdgcn_mfma_f32_16x16x32_bf16(qf[1][0], kf0, sacc[1][j], 0, 0, 0);
            sacc[0][j] = __builtin_amdgcn_mfma_f32_16x16x32_bf16(qf[0][1], kf1, sacc[0][j], 0, 0, 0);
            sacc[1][j] = __builtin_amdgcn_mfma_f32_16x16x32_bf16(qf[1][1], kf1, sacc[1][j], 0, 0, 0);
            sacc[0][j] = __builtin_amdgcn_mfma_f32_16x16x32_bf16(qf[0][2], kf2, sacc[0][j], 0, 0, 0);
            sacc[1][j] = __builtin_amdgcn_mfma_f32_16x16x32_bf16(qf[1][2], kf2, sacc[1][j], 0, 0, 0);
            sacc[0][j] = __builtin_amdgcn_mfma_f32_16x16x32_bf16(qf[0][3], kf3, sacc[0][j], 0, 0, 0);
            sacc[1][j] = __builtin_amdgcn_mfma_f32_16x16x32_bf16(qf[1][3], kf3, sacc[1][j], 0, 0, 0);
            __builtin_amdgcn_s_setprio(0);
        }

        // ---- softmax (fixed max) -> Ps (swizzled, per-wave) ----
#pragma unroll
        for (int i2 = 0; i2 < 2; i2++)
#pragma unroll
            for (int r = 0; r < 4; r++) {
                const int row = i2 * 16 + fq * 4 + r;
                char* pr = Pw + row * 128;
                const int rsw = ((fq * 4 + r) & 7) << 4;
#pragma unroll
                for (int j = 0; j < 4; j++)
                    *(__bf16*)(pr + ((j * 32 + fr * 2) ^ rsw)) =
                        (__bf16)exp2f(fmaf(sc2, sacc[i2][j][r], -M2));
            }

        // ---- PV: oa[i2][nb] over kv (kc=0,1) ----
        bf16x8 pf[2][2];
#pragma unroll
        for (int i2 = 0; i2 < 2; i2++) {
            const char* pr = Pw + (i2 * 16 + fr) * 128;
            pf[i2][0] = *(const bf16x8*)(pr + ((fq * 16) ^ sw));
            pf[i2][1] = *(const bf16x8*)(pr + ((64 + fq * 16) ^ sw));
        }
#pragma unroll
        for (int nb = 0; nb < 8; nb++) {
            const char* vr = Vb + (nb * 16 + fr) * 128;
            const bf16x8 vf0 = *(const bf16x8*)(vr + ((fq * 16) ^ sw));
            const bf16x8 vf1 = *(const bf16x8*)(vr + ((64 + fq * 16) ^ sw));
            __builtin_amdgcn_s_setprio(1);
            oa[0][nb] = __builtin_amdgcn_mfma_f32_16x16x32_bf16(pf[0][0], vf0, oa[0][nb], 0, 0, 0);
            oa[1][nb] = __builtin_amdgcn_mfma_f32_16x16x32_bf16(pf[1][0], vf0, oa[1][nb], 0, 0, 0);
            oa[0][nb] = __builtin_amdgcn_mfma_f32_16x16x32_bf16(pf[0][1], vf1, oa[0][nb], 0, 0, 0);
            oa[1][nb] = __builtin_amdgcn_mfma_f32_16x16x32_bf16(pf[1][1], vf1, oa[1][nb], 0, 0, 0);
            __builtin_amdgcn_s_setprio(0);
        }
        // l-sum: all-ones register B-fragment -> every col holds row-sum
        oa[0][8] = __builtin_amdgcn_mfma_f32_16x16x32_bf16(pf[0][0], onesb, oa[0][8], 0, 0, 0);
        oa[1][8] = __builtin_amdgcn_mfma_f32_16x16x32_bf16(pf[1][0], onesb, oa[1][8], 0, 0, 0);
        oa[0][8] = __builtin_amdgcn_mfma_f32_16x16x32_bf16(pf[0][1], onesb, oa[0][8], 0, 0, 0);
        oa[1][8] = __builtin_amdgcn_mfma_f32_16x16x32_bf16(pf[1][1], onesb, oa[1][8], 0, 0, 0);

        __builtin_amdgcn_s_barrier();      // all waves done reading buffer p
        asm volatile("" ::: "memory");
        if (it < 30) stage(p, it + 2);     // overwrite p for tile it+2
    }

    for (int i2 = 0; i2 < 2; i2++)
        for (int r = 0; r < 4; r++) {
            const float inv = 1.0f / oa[i2][8][r];
            __bf16* op = O + baseQ + (size_t)(q0 + i2 * 16 + fq * 4 + r) * 2048;
            for (int nb = 0; nb < 8; nb++)
                op[nb * 16 + fr] = (__bf16)(oa[i2][nb][r] * inv);
        }
}

// ---------------------------------------------------------------------------
extern "C" void kernel_launch(void* const* d_in, const int* in_sizes, int n_in,
                              void* d_out, int out_size, void* d_ws, size_t ws_size,
                              hipStream_t stream) {
    const float* x    = (const float*)d_in[0];
    const float* rope = (const float*)d_in[1];
    const float* wq   = (const float*)d_in[2];
    const float* wk   = (const float*)d_in[3];
    const float* wv   = (const float*)d_in[4];
    const float* wo   = (const float*)d_in[5];
    const float* qnw  = (const float*)d_in[6];
    const float* knw  = (const float*)d_in[7];
    float* out = (float*)d_out;

    static bool attr_set = false;
    if (!attr_set) {
        hipFuncSetAttribute((const void*)gemm_qkv,
                            hipFuncAttributeMaxDynamicSharedMemorySize, 131072);
        hipFuncSetAttribute((const void*)gemm_out,
                            hipFuncAttributeMaxDynamicSharedMemorySize, 131072);
        hipFuncSetAttribute((const void*)flash,
                            hipFuncAttributeMaxDynamicSharedMemorySize, 81920);
        attr_set = true;
    }

    const size_t NTOK = 2 * 2048;
    const size_t ELEMS = NTOK * 2048;            // 8388608
    __bf16* xb  = (__bf16*)d_ws;                 // 16 MB; reused as ob after flash
    __bf16* qb  = xb + ELEMS;                    // 16 MB; reused for wo_bf after flash
    __bf16* kb  = qb + ELEMS;
    __bf16* vbT = kb + ELEMS;
    __bf16* ob  = xb;
    // d_out (32 MB fp32) doubles as scratch for the concatenated bf16 QKV
    // weights (25.2 MB) — fully consumed by gemm_qkv before gemm_out writes it.
    __bf16* wqkv = (__bf16*)d_out;
    __bf16* wob  = qb;                           // wo bf16 (8 MB), written after flash

    cvt_bf16<<<(int)(ELEMS / 4) / 256, 256, 0, stream>>>(x, xb, (int)(ELEMS / 4));
    cvt3_bf16<<<3 * (2048 * 2048 / 4) / 256, 256, 0, stream>>>(wq, wk, wv, wqkv);
    gemm_qkv<<<dim3(6144 / 256, (unsigned)(NTOK / 256)), 512, 131072, stream>>>(xb, wqkv, qb, kb, vbT);
    rmsrope<<<dim3((unsigned)(NTOK * 16 / 4), 2), 256, 0, stream>>>(qb, kb, rope, qnw, knw);
    flash<<<dim3(S_LEN / 128, 2 * 16), 256, 81920, stream>>>(qb, kb, vbT, ob);
    cvt_bf16<<<(int)(2048 * 2048 / 4) / 256, 256, 0, stream>>>(wo, wob, 2048 * 2048 / 4);
    gemm_out<<<dim3(2048 / 256, (unsigned)(NTOK / 256)), 512, 131072, stream>>>(ob, wob, out);
}